// Round 1
// baseline (267.222 us; speedup 1.0000x reference)
//
#include <hip/hip_runtime.h>
#include <stdint.h>

// Problem shape (fixed by setup_inputs): B=16, C=64, H=128, W=128, fp32 throughout
#define CCH   64
#define HWSZ  16384             // H*W = 2^14
#define BATCH 16
#define NSLAB (BATCH * CCH)     // 1024 contiguous (b,c) slabs of 16384 floats
#define NPC   (BATCH * HWSZ)    // elements per channel = 262144
#define VPT   16                // float4 per thread (64 floats held in VGPRs)

static constexpr float COS_RY = 0.99500416527802576610f; // cos(0.1)
static constexpr float EPS    = 1e-6f;

typedef float fvec4 __attribute__((ext_vector_type(4)));

__device__ __forceinline__ float qpix(float x) {
    // z = cos(0.1)*cos(x); q = z + z^2 + z^3 + z^4
    float z = COS_RY * __cosf(x);
    return z * (1.0f + z * (1.0f + z * (1.0f + z)));
}

// Zero the 64 per-channel arrival counters (workspace is poisoned between
// graph replays, so this must run every iteration; it is part of the graph).
__global__ void init_kernel(uint32_t* __restrict__ cnt) {
    __hip_atomic_store(&cnt[threadIdx.x], 0u, __ATOMIC_RELAXED,
                       __HIP_MEMORY_SCOPE_AGENT);
}

// Single fused pass. One block per (b,c) slab (16384 floats, channel-uniform).
// Each thread nontemporal-loads 16 float4 (64 floats) and HOLDS them in VGPRs
// across a per-channel producer/consumer sync, so x is read from HBM exactly
// once. Total HBM traffic = 64 MiB read + 64 MiB write = the op's floor.
//
// Deadlock safety for the spin: __launch_bounds__(256,4) caps VGPR at 128
// -> 16 waves/CU -> 4 blocks/CU -> all 1024 blocks co-resident (4 x 256 CUs).
// LDS use is ~40 B; thread count 1024/CU <= 2048. All counter/partial traffic
// is agent-scope (coherent point) so cross-XCD visibility is guaranteed.
__global__ __launch_bounds__(256, 4) void fused_kernel(
        const float* __restrict__ x,
        const float* __restrict__ gamma,
        const float* __restrict__ beta,
        float* __restrict__ ws,
        float* __restrict__ out) {
    const int slab = blockIdx.x;          // b*CCH + c
    const int c    = slab & (CCH - 1);
    const int b    = slab >> 6;
    const int tid  = threadIdx.x;

    // ---- load the slab once; keep it in registers (64 VGPRs) ----
    const fvec4* __restrict__ p = (const fvec4*)(x + (size_t)slab * HWSZ);
    fvec4 v[VPT];
    #pragma unroll
    for (int i = 0; i < VPT; ++i)
        v[i] = __builtin_nontemporal_load(&p[i * 256 + tid]);

    // ---- phase 1: per-block moments ----
    float s = 0.0f, s2 = 0.0f;
    #pragma unroll
    for (int i = 0; i < VPT; ++i) {
        const float q0 = qpix(v[i].x), q1 = qpix(v[i].y);
        const float q2 = qpix(v[i].z), q3 = qpix(v[i].w);
        s  += (q0 + q1) + (q2 + q3);
        s2 += (q0 * q0 + q1 * q1) + (q2 * q2 + q3 * q3);
    }
    #pragma unroll
    for (int off = 32; off > 0; off >>= 1) {
        s  += __shfl_down(s,  off, 64);
        s2 += __shfl_down(s2, off, 64);
    }

    __shared__ float ls[4], ls2[4], sh[2];
    const int wave = tid >> 6, lane = tid & 63;
    if (lane == 0) { ls[wave] = s; ls2[wave] = s2; }
    __syncthreads();

    // ---- publish partials, arrive, and wait for the channel's 16 blocks ----
    uint32_t* cnt = (uint32_t*)(ws + 2 * NSLAB);
    if (tid == 0) {
        const float bs  = (ls[0]  + ls[1])  + (ls[2]  + ls[3]);
        const float bs2 = (ls2[0] + ls2[1]) + (ls2[2] + ls2[3]);
        const int idx = c * BATCH + b;
        __hip_atomic_store(&ws[idx], bs, __ATOMIC_RELEASE,
                           __HIP_MEMORY_SCOPE_AGENT);
        __hip_atomic_store(&ws[NSLAB + idx], bs2, __ATOMIC_RELEASE,
                           __HIP_MEMORY_SCOPE_AGENT);
        __hip_atomic_fetch_add(&cnt[c], 1u, __ATOMIC_ACQ_REL,
                               __HIP_MEMORY_SCOPE_AGENT);
        while (__hip_atomic_load(&cnt[c], __ATOMIC_ACQUIRE,
                                 __HIP_MEMORY_SCOPE_AGENT) < (uint32_t)BATCH)
            __builtin_amdgcn_s_sleep(2);
    }
    __syncthreads();   // other waves park at the barrier while tid0 polls

    // ---- reduce the channel's 16 partials, compute scale/shift ----
    if (tid < BATCH) {
        float a  = __hip_atomic_load(&ws[c * BATCH + tid], __ATOMIC_RELAXED,
                                     __HIP_MEMORY_SCOPE_AGENT);
        float a2 = __hip_atomic_load(&ws[NSLAB + c * BATCH + tid],
                                     __ATOMIC_RELAXED, __HIP_MEMORY_SCOPE_AGENT);
        #pragma unroll
        for (int off = 8; off > 0; off >>= 1) {
            a  += __shfl_down(a,  off, 16);
            a2 += __shfl_down(a2, off, 16);
        }
        if (tid == 0) {
            const float invn = 1.0f / (float)NPC;
            const float mean = a * invn;
            const float var  = a2 * invn - mean * mean;
            const float inv  = rsqrtf(var + EPS);
            const float sc   = gamma[c] * inv;
            sh[0] = sc;
            sh[1] = beta[c] - mean * sc;
        }
    }
    __syncthreads();
    const float scale = sh[0], shift = sh[1];

    // ---- phase 2: recompute q (≈1 µs chip-wide), normalize, residual, store ----
    fvec4* __restrict__ po = (fvec4*)(out + (size_t)slab * HWSZ);
    #pragma unroll
    for (int i = 0; i < VPT; ++i) {
        fvec4 o;
        o.x = fmaxf(qpix(v[i].x) * scale + shift, 0.0f) + v[i].x;
        o.y = fmaxf(qpix(v[i].y) * scale + shift, 0.0f) + v[i].y;
        o.z = fmaxf(qpix(v[i].z) * scale + shift, 0.0f) + v[i].z;
        o.w = fmaxf(qpix(v[i].w) * scale + shift, 0.0f) + v[i].w;
        __builtin_nontemporal_store(o, &po[i * 256 + tid]);
    }
}

extern "C" void kernel_launch(void* const* d_in, const int* in_sizes, int n_in,
                              void* d_out, int out_size, void* d_ws, size_t ws_size,
                              hipStream_t stream) {
    const float* x     = (const float*)d_in[0];
    const float* gamma = (const float*)d_in[1];
    const float* beta  = (const float*)d_in[2];
    float* ws = (float*)d_ws;   // [0,1024): sums, [1024,2048): sumsq, then 64 u32 counters
    uint32_t* cnt = (uint32_t*)(ws + 2 * NSLAB);

    init_kernel<<<1, CCH, 0, stream>>>(cnt);
    fused_kernel<<<NSLAB, 256, 0, stream>>>(x, gamma, beta, ws, (float*)d_out);
}

// Round 2
// 130.445 us; speedup vs baseline: 2.0485x; 2.0485x over previous
//
#include <hip/hip_runtime.h>
#include <stdint.h>

// Problem shape (fixed by setup_inputs): B=16, C=64, H=128, W=128, fp32 throughout
#define CCH   64
#define HWSZ  16384             // H*W = 2^14
#define BATCH 16
#define NSLAB (BATCH * CCH)     // 1024 contiguous (b,c) slabs of 16384 floats
#define NPC   (BATCH * HWSZ)    // elements per channel = 262144
#define VPT   16                // float4 per thread (64 floats held in VGPRs)

static constexpr float COS_RY = 0.99500416527802576610f; // cos(0.1)
static constexpr float EPS    = 1e-6f;
#define SENTINEL 0xFFFFFFFFu    // a NaN bit pattern; finite partial sums never equal it

typedef float fvec4 __attribute__((ext_vector_type(4)));

__device__ __forceinline__ float qpix(float x) {
    // z = cos(0.1)*cos(x); q = z + z^2 + z^3 + z^4
    float z = COS_RY * __cosf(x);
    return z * (1.0f + z * (1.0f + z * (1.0f + z)));
}

// Reset all 2048 partial-sum slots to SENTINEL. Agent-scope atomic stores so the
// values land at the coherence point (MALL) — fused pollers read MALL directly,
// so a plain (L2-cached) store here would leave them seeing stale data.
__global__ void init_kernel(uint32_t* __restrict__ slots) {
    const int t = threadIdx.x;
    #pragma unroll
    for (int i = 0; i < 8; ++i)
        __hip_atomic_store(&slots[i * 256 + t], SENTINEL, __ATOMIC_RELAXED,
                           __HIP_MEMORY_SCOPE_AGENT);
}

// Single fused pass, one block per (b,c) slab; x read from HBM exactly once and
// held in VGPRs across a FENCE-FREE per-channel sync:
//   producer: relaxed agent atomic store of the partial sums (bypasses L1/L2,
//             lands at MALL; value != SENTINEL is the ready flag itself)
//   consumer: relaxed agent atomic poll loads (read MALL; no buffer_inv/wbl2)
// No acquire/release anywhere -> no cache-maintenance storm (round-1 failure).
//
// Deadlock safety: amdgpu_waves_per_eu(4,4) forces VGPR <= 128 (16 waves/CU)
// AND caps occupancy at exactly 4 blocks/CU, so the 1024-block grid is fully
// and evenly co-resident on 256 CUs. LDS use ~40 B.
__global__ __launch_bounds__(256)
__attribute__((amdgpu_waves_per_eu(4, 4)))
void fused_kernel(const float* __restrict__ x,
                  const float* __restrict__ gamma,
                  const float* __restrict__ beta,
                  uint32_t* __restrict__ slots,
                  float* __restrict__ out) {
    const int slab = blockIdx.x;          // b*CCH + c
    const int c    = slab & (CCH - 1);
    const int b    = slab >> 6;
    const int tid  = threadIdx.x;

    // ---- load the slab once; keep it in registers (64 VGPRs) ----
    // Plain (cached) loads: populates L3 so later iterations re-hit it.
    const fvec4* __restrict__ p = (const fvec4*)(x + (size_t)slab * HWSZ);
    fvec4 v[VPT];
    #pragma unroll
    for (int i = 0; i < VPT; ++i)
        v[i] = p[i * 256 + tid];

    // ---- phase 1: per-block moments ----
    float s = 0.0f, s2 = 0.0f;
    #pragma unroll
    for (int i = 0; i < VPT; ++i) {
        const float q0 = qpix(v[i].x), q1 = qpix(v[i].y);
        const float q2 = qpix(v[i].z), q3 = qpix(v[i].w);
        s  += (q0 + q1) + (q2 + q3);
        s2 += (q0 * q0 + q1 * q1) + (q2 * q2 + q3 * q3);
    }
    #pragma unroll
    for (int off = 32; off > 0; off >>= 1) {
        s  += __shfl_down(s,  off, 64);
        s2 += __shfl_down(s2, off, 64);
    }

    __shared__ float ls[4], ls2[4], sh[2];
    const int wave = tid >> 6, lane = tid & 63;
    if (lane == 0) { ls[wave] = s; ls2[wave] = s2; }
    __syncthreads();

    // ---- publish this block's partial pair (relaxed, straight to MALL) ----
    if (tid == 0) {
        const float bs  = (ls[0]  + ls[1])  + (ls[2]  + ls[3]);
        const float bs2 = (ls2[0] + ls2[1]) + (ls2[2] + ls2[3]);
        uint32_t u  = __float_as_uint(bs);
        uint32_t u2 = __float_as_uint(bs2);
        // paranoia: finite sums can never be the NaN sentinel, but guard anyway
        if (u  == SENTINEL) u  ^= 1u;
        if (u2 == SENTINEL) u2 ^= 1u;
        const int idx = c * BATCH + b;
        __hip_atomic_store(&slots[idx], u, __ATOMIC_RELAXED,
                           __HIP_MEMORY_SCOPE_AGENT);
        __hip_atomic_store(&slots[NSLAB + idx], u2, __ATOMIC_RELAXED,
                           __HIP_MEMORY_SCOPE_AGENT);
    }

    // ---- lanes 0..15 poll the channel's 16 partial pairs (data == flag) ----
    if (tid < BATCH) {
        const int base = c * BATCH + tid;
        uint32_t u, u2;
        for (;;) {
            u  = __hip_atomic_load(&slots[base], __ATOMIC_RELAXED,
                                   __HIP_MEMORY_SCOPE_AGENT);
            u2 = __hip_atomic_load(&slots[NSLAB + base], __ATOMIC_RELAXED,
                                   __HIP_MEMORY_SCOPE_AGENT);
            if (u != SENTINEL && u2 != SENTINEL) break;
            __builtin_amdgcn_s_sleep(8);
        }
        float a  = __uint_as_float(u);
        float a2 = __uint_as_float(u2);
        #pragma unroll
        for (int off = 8; off > 0; off >>= 1) {
            a  += __shfl_down(a,  off, 16);
            a2 += __shfl_down(a2, off, 16);
        }
        if (tid == 0) {
            const float invn = 1.0f / (float)NPC;
            const float mean = a * invn;
            const float var  = a2 * invn - mean * mean;
            const float inv  = rsqrtf(var + EPS);
            const float sc   = gamma[c] * inv;
            sh[0] = sc;
            sh[1] = beta[c] - mean * sc;
        }
    }
    __syncthreads();   // other waves park here while wave 0 polls
    const float scale = sh[0], shift = sh[1];

    // ---- phase 2: recompute q from register-held x, normalize, residual ----
    fvec4* __restrict__ po = (fvec4*)(out + (size_t)slab * HWSZ);
    #pragma unroll
    for (int i = 0; i < VPT; ++i) {
        fvec4 o;
        o.x = fmaxf(qpix(v[i].x) * scale + shift, 0.0f) + v[i].x;
        o.y = fmaxf(qpix(v[i].y) * scale + shift, 0.0f) + v[i].y;
        o.z = fmaxf(qpix(v[i].z) * scale + shift, 0.0f) + v[i].z;
        o.w = fmaxf(qpix(v[i].w) * scale + shift, 0.0f) + v[i].w;
        __builtin_nontemporal_store(o, &po[i * 256 + tid]);
    }
}

extern "C" void kernel_launch(void* const* d_in, const int* in_sizes, int n_in,
                              void* d_out, int out_size, void* d_ws, size_t ws_size,
                              hipStream_t stream) {
    const float* x     = (const float*)d_in[0];
    const float* gamma = (const float*)d_in[1];
    const float* beta  = (const float*)d_in[2];
    uint32_t* slots = (uint32_t*)d_ws;   // 2048 u32: [0,1024) sums, [1024,2048) sumsq

    init_kernel<<<1, 256, 0, stream>>>(slots);
    fused_kernel<<<NSLAB, 256, 0, stream>>>(x, gamma, beta, slots, (float*)d_out);
}

// Round 3
// 122.051 us; speedup vs baseline: 2.1894x; 1.0688x over previous
//
#include <hip/hip_runtime.h>
#include <stdint.h>

// Problem shape (fixed by setup_inputs): B=16, C=64, H=128, W=128, fp32 throughout
#define CCH   64
#define HWSZ  16384             // H*W = 2^14
#define BATCH 16
#define NSLAB (BATCH * CCH)     // 1024 contiguous (b,c) slabs of 16384 floats
#define NPC   (BATCH * HWSZ)    // elements per channel = 262144
#define VPT   16                // float4 iterations per thread (streamed, NOT held)

static constexpr float COS_RY = 0.99500416527802576610f; // cos(0.1)
static constexpr float EPS    = 1e-6f;
#define SENTINEL 0xFFFFFFFFu    // NaN bit pattern; finite partial sums never equal it

typedef float fvec4 __attribute__((ext_vector_type(4)));

__device__ __forceinline__ float qpix(float x) {
    // z = cos(0.1)*cos(x); q = z + z^2 + z^3 + z^4
    float z = COS_RY * __cosf(x);
    return z * (1.0f + z * (1.0f + z * (1.0f + z)));
}

// Reset all 2048 partial-sum slots to SENTINEL. Agent-scope atomic stores so the
// values land at the coherence point — pollers read there, so a plain (cached)
// store could leave them seeing stale data.
__global__ void init_kernel(uint32_t* __restrict__ slots) {
    const int t = threadIdx.x;
    #pragma unroll
    for (int i = 0; i < 8; ++i)
        __hip_atomic_store(&slots[i * 256 + t], SENTINEL, __ATOMIC_RELAXED,
                           __HIP_MEMORY_SCOPE_AGENT);
}

// Single fused pass, one block per (b,c) slab, STREAMING both phases:
//  phase A: read slab from HBM, accumulate moments (nothing held in VGPRs ->
//           ~48 VGPRs, no spill; rounds 1-2 proved the allocator will not give
//           this kernel the 80+ regs needed to hold x, spilling 17 MB instead)
//  sync:    fence-free sentinel handshake (relaxed agent atomics; the partial
//           sum's value IS the ready flag; no buffer_inv/wbl2 storm)
//  phase B: RE-READ the same 64 KB — x is L2/MALL-resident (64 MiB data vs
//           256 MiB memory-side Infinity Cache; this block just touched it),
//           so the re-read does not hit HBM. Normalize, ReLU, residual, nt-store.
//
// Deadlock safety for the spin: grid = 1024 blocks of 256 thr needs 4 blocks/CU
// co-resident on 256 CUs; with ~48 VGPRs and ~48 B LDS the thread-capacity
// limit (8 blocks/CU) is the binding one, so full co-residency is guaranteed.
__global__ __launch_bounds__(256)
void fused_kernel(const float* __restrict__ x,
                  const float* __restrict__ gamma,
                  const float* __restrict__ beta,
                  uint32_t* __restrict__ slots,
                  float* __restrict__ out) {
    const int slab = blockIdx.x;          // b*CCH + c
    const int c    = slab & (CCH - 1);
    const int b    = slab >> 6;
    const int tid  = threadIdx.x;

    const fvec4* __restrict__ p = (const fvec4*)(x + (size_t)slab * HWSZ);

    // ---- phase A: streaming moments (load -> accumulate, nothing held) ----
    float s = 0.0f, s2 = 0.0f;
    #pragma unroll
    for (int i = 0; i < VPT; ++i) {
        const fvec4 v = p[i * 256 + tid];
        const float q0 = qpix(v.x), q1 = qpix(v.y);
        const float q2 = qpix(v.z), q3 = qpix(v.w);
        s  += (q0 + q1) + (q2 + q3);
        s2 += (q0 * q0 + q1 * q1) + (q2 * q2 + q3 * q3);
    }
    #pragma unroll
    for (int off = 32; off > 0; off >>= 1) {
        s  += __shfl_down(s,  off, 64);
        s2 += __shfl_down(s2, off, 64);
    }

    __shared__ float ls[4], ls2[4], sh[2];
    const int wave = tid >> 6, lane = tid & 63;
    if (lane == 0) { ls[wave] = s; ls2[wave] = s2; }
    __syncthreads();

    // ---- publish this block's partial pair (relaxed, to the coherence point) ----
    if (tid == 0) {
        const float bs  = (ls[0]  + ls[1])  + (ls[2]  + ls[3]);
        const float bs2 = (ls2[0] + ls2[1]) + (ls2[2] + ls2[3]);
        uint32_t u  = __float_as_uint(bs);
        uint32_t u2 = __float_as_uint(bs2);
        if (u  == SENTINEL) u  ^= 1u;     // finite sums can't be the NaN sentinel,
        if (u2 == SENTINEL) u2 ^= 1u;     // but guard anyway
        const int idx = c * BATCH + b;
        __hip_atomic_store(&slots[idx], u, __ATOMIC_RELAXED,
                           __HIP_MEMORY_SCOPE_AGENT);
        __hip_atomic_store(&slots[NSLAB + idx], u2, __ATOMIC_RELAXED,
                           __HIP_MEMORY_SCOPE_AGENT);
    }

    // ---- lanes 0..15 poll the channel's 16 partial pairs (data == flag) ----
    if (tid < BATCH) {
        const int base = c * BATCH + tid;
        uint32_t u, u2;
        for (;;) {
            u  = __hip_atomic_load(&slots[base], __ATOMIC_RELAXED,
                                   __HIP_MEMORY_SCOPE_AGENT);
            u2 = __hip_atomic_load(&slots[NSLAB + base], __ATOMIC_RELAXED,
                                   __HIP_MEMORY_SCOPE_AGENT);
            if (u != SENTINEL && u2 != SENTINEL) break;
            __builtin_amdgcn_s_sleep(4);
        }
        float a  = __uint_as_float(u);
        float a2 = __uint_as_float(u2);
        #pragma unroll
        for (int off = 8; off > 0; off >>= 1) {
            a  += __shfl_down(a,  off, 16);
            a2 += __shfl_down(a2, off, 16);
        }
        if (tid == 0) {
            const float invn = 1.0f / (float)NPC;
            const float mean = a * invn;
            const float var  = a2 * invn - mean * mean;
            const float inv  = rsqrtf(var + EPS);
            const float sc   = gamma[c] * inv;
            sh[0] = sc;
            sh[1] = beta[c] - mean * sc;
        }
    }
    __syncthreads();   // other waves park here while wave 0 polls
    const float scale = sh[0], shift = sh[1];

    // ---- phase B: re-read slab (L2/MALL hit), normalize, residual, store ----
    fvec4* __restrict__ po = (fvec4*)(out + (size_t)slab * HWSZ);
    #pragma unroll
    for (int i = 0; i < VPT; ++i) {
        const fvec4 v = p[i * 256 + tid];
        fvec4 o;
        o.x = fmaxf(qpix(v.x) * scale + shift, 0.0f) + v.x;
        o.y = fmaxf(qpix(v.y) * scale + shift, 0.0f) + v.y;
        o.z = fmaxf(qpix(v.z) * scale + shift, 0.0f) + v.z;
        o.w = fmaxf(qpix(v.w) * scale + shift, 0.0f) + v.w;
        __builtin_nontemporal_store(o, &po[i * 256 + tid]);
    }
}

extern "C" void kernel_launch(void* const* d_in, const int* in_sizes, int n_in,
                              void* d_out, int out_size, void* d_ws, size_t ws_size,
                              hipStream_t stream) {
    const float* x     = (const float*)d_in[0];
    const float* gamma = (const float*)d_in[1];
    const float* beta  = (const float*)d_in[2];
    uint32_t* slots = (uint32_t*)d_ws;   // 2048 u32: [0,1024) sums, [1024,2048) sumsq

    init_kernel<<<1, 256, 0, stream>>>(slots);
    fused_kernel<<<NSLAB, 256, 0, stream>>>(x, gamma, beta, slots, (float*)d_out);
}

// Round 4
// 119.205 us; speedup vs baseline: 2.2417x; 1.0239x over previous
//
#include <hip/hip_runtime.h>
#include <stdint.h>

// Problem shape (fixed by setup_inputs): B=16, C=64, H=128, W=128, fp32 throughout
#define CCH   64
#define HWSZ  16384            // H*W = 2^14
#define BATCH 16
#define NSLAB (BATCH * CCH)    // 1024 contiguous (b,c) slabs of 16384 floats
#define SEGS  4                // stats segments per slab
#define NSEG  (NSLAB * SEGS)   // 4096 stats blocks / partials per moment
#define NPC   (BATCH * HWSZ)   // elements per channel = 262144
#define NTOT  (BATCH * CCH * HWSZ)

static constexpr float COS_RY = 0.99500416527802576610f; // cos(0.1)
static constexpr float EPS    = 1e-6f;

typedef float fvec4 __attribute__((ext_vector_type(4)));
typedef float fvec2 __attribute__((ext_vector_type(2)));

// Packed-FP32-friendly qpix on a float2: the two v_cos stay scalar (trans unit),
// but the scale + degree-4 polynomial become <2 x float> ops which the gfx950
// backend selects as v_pk_mul_f32 / v_pk_fma_f32 — halving the VALU cost of the
// dominant per-element math (both passes sit at the compute/memory crossover).
__device__ __forceinline__ fvec2 qpix2(float x0, float x1) {
    fvec2 c;
    c.x = __cosf(x0);
    c.y = __cosf(x1);
    const fvec2 z = COS_RY * c;
    return z * (1.0f + z * (1.0f + z * (1.0f + z)));   // z + z^2 + z^3 + z^4
}

// Pass 1: per-(channel,segment) partial sums, plain stores (no memset, no atomics).
// Block blk: slab = blk>>2 (= b*CCH+c), seg = blk&3. Each block covers 4096 floats.
// Partial layout: ps[c*64 + b*4 + seg] so each channel's 64 partials are contiguous.
__global__ __launch_bounds__(256) void stats_kernel(
        const float* __restrict__ x, float* __restrict__ ps) {
    const int blk  = blockIdx.x;          // 0..4095
    const int slab = blk >> 2;            // b*CCH + c
    const int seg  = blk & (SEGS - 1);
    const int c    = slab & (CCH - 1);
    const int b    = slab >> 6;
    const float4* __restrict__ p =
        (const float4*)(x + (size_t)slab * HWSZ + (size_t)seg * 4096);

    fvec2 sv = {0.0f, 0.0f}, s2v = {0.0f, 0.0f};
    #pragma unroll
    for (int it = 0; it < 4; ++it) {      // 4096 / (256*4) = 4
        const float4 v = p[it * 256 + (int)threadIdx.x];
        const fvec2 qa = qpix2(v.x, v.y);
        const fvec2 qb = qpix2(v.z, v.w);
        sv  += qa + qb;                   // v_pk_add_f32
        s2v += qa * qa + qb * qb;         // v_pk_fma_f32 x2
    }
    float s  = sv.x + sv.y;
    float s2 = s2v.x + s2v.y;
    #pragma unroll
    for (int off = 32; off > 0; off >>= 1) {
        s  += __shfl_down(s,  off, 64);
        s2 += __shfl_down(s2, off, 64);
    }
    __shared__ float ls[4], ls2[4];
    const int wave = threadIdx.x >> 6, lane = threadIdx.x & 63;
    if (lane == 0) { ls[wave] = s; ls2[wave] = s2; }
    __syncthreads();
    if (threadIdx.x == 0) {
        const int idx = c * 64 + b * SEGS + seg;
        ps[idx]        = (ls[0]  + ls[1])  + (ls[2]  + ls[3]);
        ps[NSEG + idx] = (ls2[0] + ls2[1]) + (ls2[2] + ls2[3]);
    }
}

// Pass 2: block = 4096-float channel-uniform tile (4 per slab, 4096 blocks).
// First wave reduces the channel's 64 partials (hidden under the 4 in-flight
// float4 loads); all threads then apply
// y = relu((q-mean)*rsqrt(var+eps)*gamma+beta) + x with nontemporal stores.
// x re-read hits MALL (64 MiB data vs 256 MiB memory-side cache, just touched
// by pass 1), so HBM traffic is write-only here.
__global__ __launch_bounds__(256) void apply_kernel(
        const float* __restrict__ x,
        const float* __restrict__ gamma,
        const float* __restrict__ beta,
        const float* __restrict__ ps,
        float* __restrict__ out) {
    const size_t blockBase = (size_t)blockIdx.x * 4096;   // floats
    const int c = (int)((blockBase >> 14) & (CCH - 1));   // uniform per block
    const int tid = threadIdx.x;

    // issue main loads early (independent of the reduction)
    const float4* __restrict__ p = (const float4*)(x + blockBase);
    const float4 v0 = p[tid];
    const float4 v1 = p[256 + tid];
    const float4 v2 = p[512 + tid];
    const float4 v3 = p[768 + tid];

    __shared__ float sh[2];
    if (tid < 64) {
        float a  = ps[c * 64 + tid];
        float a2 = ps[NSEG + c * 64 + tid];
        #pragma unroll
        for (int off = 32; off > 0; off >>= 1) {
            a  += __shfl_down(a,  off, 64);
            a2 += __shfl_down(a2, off, 64);
        }
        if (tid == 0) {
            const float invn = 1.0f / (float)NPC;
            const float mean = a * invn;
            const float var  = a2 * invn - mean * mean;
            const float inv  = rsqrtf(var + EPS);
            const float sc   = gamma[c] * inv;
            sh[0] = sc;
            sh[1] = beta[c] - mean * sc;
        }
    }
    __syncthreads();
    const fvec2 scale = {sh[0], sh[0]};
    const fvec2 shift = {sh[1], sh[1]};
    const fvec2 zero  = {0.0f, 0.0f};

    fvec4* __restrict__ po = (fvec4*)(out + blockBase);
    const float4 vin[4] = {v0, v1, v2, v3};
    #pragma unroll
    for (int i = 0; i < 4; ++i) {
        const float4 v = vin[i];
        // packed normalize+relu+residual: v_pk_fma / v_pk_max / v_pk_add
        const fvec2 xa = {v.x, v.y}, xb = {v.z, v.w};
        fvec2 ya = qpix2(v.x, v.y) * scale + shift;
        fvec2 yb = qpix2(v.z, v.w) * scale + shift;
        ya = __builtin_elementwise_max(ya, zero) + xa;
        yb = __builtin_elementwise_max(yb, zero) + xb;
        fvec4 o = {ya.x, ya.y, yb.x, yb.y};
        __builtin_nontemporal_store(o, &po[i * 256 + tid]);
    }
}

extern "C" void kernel_launch(void* const* d_in, const int* in_sizes, int n_in,
                              void* d_out, int out_size, void* d_ws, size_t ws_size,
                              hipStream_t stream) {
    const float* x     = (const float*)d_in[0];
    const float* gamma = (const float*)d_in[1];
    const float* beta  = (const float*)d_in[2];
    float* out = (float*)d_out;
    float* ps  = (float*)d_ws;   // 2*NSEG floats = 32 KB, fully overwritten by stats

    stats_kernel<<<NSEG, 256, 0, stream>>>(x, ps);

    const int apply_blocks = NTOT / 4096;   // 4096
    apply_kernel<<<apply_blocks, 256, 0, stream>>>(x, gamma, beta, ps, out);
}